// Round 2
// 242.719 us; speedup vs baseline: 1.1928x; 1.1928x over previous
//
#include <hip/hip_runtime.h>

// MVC log-domain 3D conv.
// Preferred path (needs ~56.6 MB workspace):
//   K1 (mvc_log):  logx[b][voxel][ci] = bf16(log x)  -- streaming, coalesced, ci-innermost
//   K2 (mvc_conv): implicit-GEMM conv on MFMA, staging via global_load_lds (no reg staging,
//                  no in-kernel log), 4-slice rolling z buffer, ONE barrier per z-plane.
//                  logM folded in as a 15th MFMA (A = 1/16 on the dx=1 k-slots of the
//                  center-tap B fragment) -> mean_ci logx(center) in fp32.
// Fallback path (16 KB workspace): previous harness-verified fused kernel (mvc_main).
//
// K2 geometry: TY=2 output rows, full-x 96, ZC=12 planes/block.
//   LDS = 4 slices x 4 rows x 98 cols x 16ci bf16 (12544 B) + 1 KB trash = 51200 B
//   -> 3 blocks/CU, 12 waves/CU.  Grid 768 = 2b x 8zch x 48yt = exactly 3/CU.

#define VOX  884736            // 96^3
#define SLX  98                // 1 + 96 + 1 pad cols
#define ROWS (SLX * 16)        // 1568 shorts per LDS row
#define SROWS 4                // rows per slice (TY + 2 halo)
#define SSs  (SROWS * ROWS)    // 6272 shorts per slice
#define SSb  (SSs * 2)         // 12544 bytes per slice
#define NSL  4
#define TY   2
#define ZC   12

typedef __attribute__((ext_vector_type(8))) short short8;
typedef __attribute__((ext_vector_type(4))) float f32x4;

__device__ __forceinline__ unsigned short f2bf_rne(float f) {
    unsigned u = __float_as_uint(f);
    u += 0x7fff + ((u >> 16) & 1);
    return (unsigned short)(u >> 16);
}
__device__ __forceinline__ float bf2f(short s) {
    return __uint_as_float(((unsigned)(unsigned short)s) << 16);
}

// ---------------------------------------------------------------------------
// Weight reorg (shared by all paths): w3[cout][k=448] MFMA A-order, wadj = 1-sum(w).
// ---------------------------------------------------------------------------
__global__ void mvc_reorg(const float* __restrict__ w,
                          short* __restrict__ w3,
                          float* __restrict__ wadj) {
    int i = blockIdx.x * 256 + threadIdx.x;
    if (i < 16 * 448) {
        int n = i / 448, k = i % 448;
        int p = k >> 5, q = (k >> 3) & 3, j = k & 7;
        int qhi = q >> 1, ci = (q & 1) * 8 + j;
        int tap;
        bool valid = true;
        if (p < 9)        tap = (p / 3) * 9 + (p % 3) * 3 + qhi;
        else if (p < 12)  tap = (p - 9) * 9 + qhi * 3 + 2;
        else if (p == 12) tap = qhi * 9 + 8;
        else { tap = 26; valid = (qhi == 0); }
        float v = valid ? w[n * 432 + tap * 16 + ci] : 0.0f;
        w3[i] = (short)f2bf_rne(v);
    }
    if (i < 16) {
        const float* pw = w + i * 432;
        float s = 0.0f;
        for (int t = 0; t < 432; ++t) s += pw[t];
        wadj[i] = 1.0f - s;
    }
}

// ---------------------------------------------------------------------------
// K1: log transform + transpose to [b][voxel][ci] bf16 (32 B records).
// Grid nb*3456; x pre-offset per batch when nb==1.
// ---------------------------------------------------------------------------
__global__ void __launch_bounds__(256)
mvc_log(const float* __restrict__ x, short* __restrict__ lx) {
    const int id = blockIdx.x;
    const int b = id / 3456;
    const size_t v = (size_t)(id - b * 3456) * 256 + threadIdx.x;
    const float* xb = x + (size_t)b * 16 * VOX + v;
    unsigned rbuf[8];
    #pragma unroll
    for (int c = 0; c < 8; ++c) {
        unsigned lo = f2bf_rne(__logf(xb[(size_t)(2 * c) * VOX]));
        unsigned hi = f2bf_rne(__logf(xb[(size_t)(2 * c + 1) * VOX]));
        rbuf[c] = lo | (hi << 16);
    }
    unsigned* dst = (unsigned*)(lx + ((size_t)b * VOX + v) * 16);
    *(uint4*)dst       = make_uint4(rbuf[0], rbuf[1], rbuf[2], rbuf[3]);
    *(uint4*)(dst + 4) = make_uint4(rbuf[4], rbuf[5], rbuf[6], rbuf[7]);
}

// ---------------------------------------------------------------------------
// K2: conv + exp.  LDS 51200 B -> 3 blocks/CU.  Grid nb*384.
// lx is an nb-batch logx buffer; out pre-offset per batch when nb==1.
// ---------------------------------------------------------------------------
__global__ void __launch_bounds__(256, 3)
mvc_conv(const short* __restrict__ lx,
         const short* __restrict__ w3,
         const float* __restrict__ wadj,
         float* __restrict__ out) {
    __shared__ __align__(16) short tile[NSL * SSs + 512];   // + 1 KB trash

    const int tid  = threadIdx.x;
    const int lane = tid & 63;
    const int wv   = tid >> 6;
    const int mn   = lane & 15;
    const int q    = lane >> 4;
    const int qlo  = q & 1;
    const int qhi  = q >> 1;

    // XCD swizzle: 6 consecutive y-tiles per XCD (y-halo L2 capture).
    int id  = blockIdx.x;
    int xcd = id & 7, g = id >> 3;
    int yt  = xcd * 6 + g % 6;            // 0..47
    int rr  = g / 6;
    int zch = rr % 8, b = rr / 8;
    const int y0 = yt * TY;
    const int z0 = zch * ZC;

    const short* lxb = lx + (size_t)b * VOX * 16;
    float* ob = out + (size_t)b * 16 * VOX;

    // loop-invariant: weight A-fragments + wadj + the logM "ones" fragment
    short8 bfr[14];
    #pragma unroll
    for (int p = 0; p < 14; ++p)
        bfr[p] = *(const short8*)(w3 + mn * 448 + p * 32 + q * 8);
    const float4 wv4 = *(const float4*)(wadj + 4 * q);
    const float wa[4] = {wv4.x, wv4.y, wv4.z, wv4.w};
    const short oc = qhi ? (short)0x3D80 : (short)0;    // 1/16 bf16 on dx=1 k-slots
    const short8 aones = {oc, oc, oc, oc, oc, oc, oc, oc};

    // ---- staging: one wave per slice row, 3x 1024 B global_load_lds chunks ----
    auto stage = [&](int zp) {            // 0 <= zp < 96 guaranteed by caller
        const int sl = zp & 3;
        const int gy = y0 - 1 + wv;
        const bool vr = (unsigned)gy < 96u;
        const int gyc = vr ? gy : 0;
        const short* gsrc = lxb + (size_t)(zp * 9216 + gyc * 96) * 16 + lane * 8;
        short* lrow = tile + sl * SSs + (wv * SLX + 1) * 16;
        short* ltr  = tile + NSL * SSs;   // trash sink for out-of-range rows
        #pragma unroll
        for (int k = 0; k < 3; ++k) {
            short* dst = vr ? (lrow + k * 512) : ltr;
            __builtin_amdgcn_global_load_lds(
                (const __attribute__((address_space(1))) unsigned int*)(const void*)(gsrc + k * 512),
                (__attribute__((address_space(3))) unsigned int*)(void*)dst,
                16, 0, 0);
        }
    };
    auto zero_slice = [&](int sl) {       // 12544 B = 784 x 16 B
        #pragma unroll
        for (int i = 0; i < 4; ++i) {
            int c = tid + i * 256;
            if (c < 784)
                *(f32x4*)((char*)tile + sl * SSb + c * 16) = (f32x4){0.f, 0.f, 0.f, 0.f};
        }
    };

    // ---- prologue: zero pads / boundary rows, stage planes z0-1, z0, z0+1 ----
    if (tid < 64) {                       // pad cols 0 and 97, all slices/rows
        int s = tid >> 4, rest = tid & 15;
        int row = rest >> 2, side = (rest >> 1) & 1, half = tid & 1;
        *(f32x4*)((char*)tile + s * SSb + (row * SLX + side * 97) * 32 + half * 16)
            = (f32x4){0.f, 0.f, 0.f, 0.f};
    }
    if (yt == 0 || yt == 47) {            // fully out-of-range y row stays zero
        int row = (yt == 0) ? 0 : 3;
        #pragma unroll
        for (int s = 0; s < 4; ++s)
            if (tid < 196)
                *(f32x4*)((char*)tile + s * SSb + row * 3136 + tid * 16)
                    = (f32x4){0.f, 0.f, 0.f, 0.f};
    }
    if (z0 == 0) zero_slice(3); else stage(z0 - 1);
    stage(z0);
    stage(z0 + 1);

    // ---- rolling z-march: ONE barrier per plane; gll latency hidden by MFMA ----
    #pragma unroll 1
    for (int zi = 0; zi < ZC; ++zi) {
        const int z = z0 + zi;
        asm volatile("s_waitcnt vmcnt(0)" ::: "memory");  // all prior gll landed
        __syncthreads();                                   // visible to all waves
        if (zi < ZC - 1) {
            const int zp = z + 2;
            if (zp < 96) stage(zp);       // into slice (z+2)&3 -- not read this iter
            else         zero_slice(zp & 3);
        }
        __builtin_amdgcn_sched_barrier(0);

        const int B0 = ((z + 3) & 3) * SSs;   // plane z-1
        const int B1 = (z & 3) * SSs;         // plane z
        const int B2 = ((z + 1) & 3) * SSs;   // plane z+1
        const int r  = wv >> 1;               // wave's output y row (0/1)
        const int xh = wv & 1;                // wave's x half
        const int Lb = mn * 16 + qlo * 8 + r * ROWS + qhi * 16;

        #pragma unroll
        for (int jj = 0; jj < 3; ++jj) {
            const int j = xh * 3 + jj;
            const short* vA0 = tile + (Lb + j * 256 + B0);
            const short* vA1 = tile + (Lb + j * 256 + B1);
            const short* vA2 = tile + (Lb + j * 256 + B2);
            const short* vB0 = vA0 + 32 + qhi * 1552;      // dx=2, dy=qhi fold
            const short* vB1 = vA1 + 32 + qhi * 1552;
            const short* vB2 = vA2 + 32 + qhi * 1552;
            const short* vD  = vB2 + (3136 - qhi * 1584);  // dz2,dy2,dx2 (both halves)
            const short* vC  = vD - B2 + (qhi ? B1 : B0);  // dz=qhi, dy2, dx2

            f32x4 acc = {0.f, 0.f, 0.f, 0.f};
            acc = __builtin_amdgcn_mfma_f32_16x16x32_bf16(bfr[0],  *(const short8*)(vA0),        acc, 0, 0, 0);
            acc = __builtin_amdgcn_mfma_f32_16x16x32_bf16(bfr[1],  *(const short8*)(vA0 + 1568), acc, 0, 0, 0);
            acc = __builtin_amdgcn_mfma_f32_16x16x32_bf16(bfr[2],  *(const short8*)(vA0 + 3136), acc, 0, 0, 0);
            acc = __builtin_amdgcn_mfma_f32_16x16x32_bf16(bfr[3],  *(const short8*)(vA1),        acc, 0, 0, 0);
            acc = __builtin_amdgcn_mfma_f32_16x16x32_bf16(bfr[4],  *(const short8*)(vA1 + 1568), acc, 0, 0, 0);
            acc = __builtin_amdgcn_mfma_f32_16x16x32_bf16(bfr[5],  *(const short8*)(vA1 + 3136), acc, 0, 0, 0);
            acc = __builtin_amdgcn_mfma_f32_16x16x32_bf16(bfr[6],  *(const short8*)(vA2),        acc, 0, 0, 0);
            acc = __builtin_amdgcn_mfma_f32_16x16x32_bf16(bfr[7],  *(const short8*)(vA2 + 1568), acc, 0, 0, 0);
            acc = __builtin_amdgcn_mfma_f32_16x16x32_bf16(bfr[8],  *(const short8*)(vA2 + 3136), acc, 0, 0, 0);
            acc = __builtin_amdgcn_mfma_f32_16x16x32_bf16(bfr[9],  *(const short8*)(vB0),        acc, 0, 0, 0);
            acc = __builtin_amdgcn_mfma_f32_16x16x32_bf16(bfr[10], *(const short8*)(vB1),        acc, 0, 0, 0);
            acc = __builtin_amdgcn_mfma_f32_16x16x32_bf16(bfr[11], *(const short8*)(vB2),        acc, 0, 0, 0);
            acc = __builtin_amdgcn_mfma_f32_16x16x32_bf16(bfr[12], *(const short8*)(vC),         acc, 0, 0, 0);
            acc = __builtin_amdgcn_mfma_f32_16x16x32_bf16(bfr[13], *(const short8*)(vD),         acc, 0, 0, 0);

            // logM via MFMA: mean_ci of center tap (reuses the vA1+1568 ds_read)
            f32x4 am = __builtin_amdgcn_mfma_f32_16x16x32_bf16(
                aones, *(const short8*)(vA1 + 1568), (f32x4){0.f, 0.f, 0.f, 0.f}, 0, 0, 0);
            const float lm = am[0];

            // epilogue: D row m = 4q+t = cout, col n = mn = x -> 64 B-run stores
            float* op = ob + (size_t)(4 * q) * VOX
                      + (((size_t)z * 96 + (y0 + r)) * 96 + j * 16 + mn);
            #pragma unroll
            for (int t = 0; t < 4; ++t) {
                float e = fminf(fmaf(wa[t], lm, acc[t]), 88.0f);
                op[(size_t)t * VOX] = __expf(e);
            }
        }
    }
}

// ---------------------------------------------------------------------------
// Fallback: previous harness-verified fused kernel (289.8 us), 16 KB workspace.
// ---------------------------------------------------------------------------
#define FSLY  6
#define FROWS (SLX * 16)
#define FSS   (FSLY * FROWS)
#define FTY   4
#define FZC   6

__global__ void __launch_bounds__(256, 2)
mvc_main(const float* __restrict__ x,
         const short* __restrict__ w3,
         const float* __restrict__ wadj,
         float* __restrict__ out) {
    __shared__ __align__(16) short tile[3 * FSS];
    __shared__ float logMt[FTY * 96];

    const int tid  = threadIdx.x;
    const int lane = tid & 63;
    const int wv   = tid >> 6;
    const int mn   = lane & 15;
    const int q    = lane >> 4;
    const int qlo  = q & 1;
    const int qhi  = q >> 1;

    int id  = blockIdx.x;
    int xcd = id & 7, g = id >> 3;
    int yt  = xcd * 3 + g % 3;
    int rr  = g / 3;
    int zch = rr & 15, b = rr >> 4;
    const int y0 = yt * FTY;
    const int z0 = zch * FZC;

    const float* xb = x + (size_t)b * 16 * VOX;
    float* ob = out + (size_t)b * 16 * VOX;

    short8 bfr[14];
    #pragma unroll
    for (int p = 0; p < 14; ++p)
        bfr[p] = *(const short8*)(w3 + mn * 448 + p * 32 + q * 8);
    const float4 wv4 = *(const float4*)(wadj + 4 * q);
    const float wa[4] = {wv4.x, wv4.y, wv4.z, wv4.w};

    if (tid < 288) {
        int d = tid & 7, vv = tid >> 3;
        int bu = vv / 12, rv = vv % 12;
        int row = rv >> 1, side = rv & 1;
        ((unsigned*)tile)[bu * (FSS / 2) + (row * SLX + side * 97) * 8 + d] = 0u;
    }

    float2 h[5][4];

    auto load_plane = [&](int zp) {
        bool zin = (unsigned)zp < 96u;
        #pragma unroll
        for (int it = 0; it < 5; ++it) {
            if (it == 4 && tid >= 128) break;
            int slot = tid + it * 256;
            int cq = slot & 3;
            int t  = slot >> 2;
            int xp = t % 48;
            int y  = t / 48;
            int gy = y0 + y - 1;
            bool inb = zin && ((unsigned)gy < 96u);
            const float* p0 = xb + (size_t)(4 * cq) * VOX
                            + ((zp * 96 + gy) * 96 + 2 * xp);
            h[it][0] = inb ? *(const float2*)(p0)            : make_float2(1.f, 1.f);
            h[it][1] = inb ? *(const float2*)(p0 + VOX)      : make_float2(1.f, 1.f);
            h[it][2] = inb ? *(const float2*)(p0 + 2 * VOX)  : make_float2(1.f, 1.f);
            h[it][3] = inb ? *(const float2*)(p0 + 3 * VOX)  : make_float2(1.f, 1.f);
        }
    };
    auto write_plane = [&](int zp) {
        short* sb = tile + ((zp + 3) % 3) * FSS;
        #pragma unroll
        for (int it = 0; it < 5; ++it) {
            if (it == 4 && tid >= 128) break;
            int slot = tid + it * 256;
            int cq = slot & 3;
            int t  = slot >> 2;
            int xp = t % 48;
            int y  = t / 48;
            unsigned a0 = f2bf_rne(__logf(h[it][0].x)), a1 = f2bf_rne(__logf(h[it][1].x));
            unsigned a2 = f2bf_rne(__logf(h[it][2].x)), a3 = f2bf_rne(__logf(h[it][3].x));
            unsigned c0 = f2bf_rne(__logf(h[it][0].y)), c1 = f2bf_rne(__logf(h[it][1].y));
            unsigned c2 = f2bf_rne(__logf(h[it][2].y)), c3 = f2bf_rne(__logf(h[it][3].y));
            unsigned* dst = (unsigned*)(sb + (y * SLX + 1 + 2 * xp) * 16 + 4 * cq);
            *(uint2*)(dst)     = make_uint2(a0 | (a1 << 16), a2 | (a3 << 16));
            *(uint2*)(dst + 8) = make_uint2(c0 | (c1 << 16), c2 | (c3 << 16));
        }
    };
    auto do_logM = [&](int z) {
        const short* cb = tile + (z % 3) * FSS;
        #pragma unroll
        for (int it = 0; it < 2; ++it) {
            if (it == 1 && tid >= 128) break;
            int v = tid + it * 256;
            int xx = v % 96, yy = v / 96;
            const short* p = cb + ((yy + 1) * SLX + (xx + 1)) * 16;
            short8 h0 = *(const short8*)p;
            short8 h1 = *(const short8*)(p + 8);
            float s = 0.f;
            #pragma unroll
            for (int c = 0; c < 8; ++c) s += bf2f(h0[c]) + bf2f(h1[c]);
            logMt[v] = s * 0.0625f;
        }
    };

    load_plane(z0 - 1); write_plane(z0 - 1);
    load_plane(z0);     write_plane(z0);
    load_plane(z0 + 1); write_plane(z0 + 1);
    __syncthreads();

    for (int zi = 0; zi < FZC; ++zi) {
        const int z = z0 + zi;
        const bool st = (zi < FZC - 1);
        if (st) load_plane(z + 2);
        do_logM(z);
        __syncthreads();

        const int B0 = ((z + 2) % 3) * FSS;
        const int B1 = (z % 3) * FSS;
        const int B2 = ((z + 1) % 3) * FSS;
        const int Lb = mn * 16 + qlo * 8 + wv * FROWS + qhi * 16;

        #pragma unroll
        for (int j = 0; j < 6; ++j) {
            const short* vA0 = tile + (Lb + j * 256 + B0);
            const short* vA1 = tile + (Lb + j * 256 + B1);
            const short* vA2 = tile + (Lb + j * 256 + B2);
            const short* vB0 = vA0 + 32 + qhi * 1552;
            const short* vB1 = vA1 + 32 + qhi * 1552;
            const short* vB2 = vA2 + 32 + qhi * 1552;
            const short* vD  = vB2 + (3136 - qhi * 1584);
            const short* vC  = vD - B2 + (qhi ? B1 : B0);

            f32x4 acc = {0.f, 0.f, 0.f, 0.f};
            acc = __builtin_amdgcn_mfma_f32_16x16x32_bf16(bfr[0],  *(const short8*)(vA0),        acc, 0, 0, 0);
            acc = __builtin_amdgcn_mfma_f32_16x16x32_bf16(bfr[1],  *(const short8*)(vA0 + 1568), acc, 0, 0, 0);
            acc = __builtin_amdgcn_mfma_f32_16x16x32_bf16(bfr[2],  *(const short8*)(vA0 + 3136), acc, 0, 0, 0);
            acc = __builtin_amdgcn_mfma_f32_16x16x32_bf16(bfr[3],  *(const short8*)(vA1),        acc, 0, 0, 0);
            acc = __builtin_amdgcn_mfma_f32_16x16x32_bf16(bfr[4],  *(const short8*)(vA1 + 1568), acc, 0, 0, 0);
            acc = __builtin_amdgcn_mfma_f32_16x16x32_bf16(bfr[5],  *(const short8*)(vA1 + 3136), acc, 0, 0, 0);
            acc = __builtin_amdgcn_mfma_f32_16x16x32_bf16(bfr[6],  *(const short8*)(vA2),        acc, 0, 0, 0);
            acc = __builtin_amdgcn_mfma_f32_16x16x32_bf16(bfr[7],  *(const short8*)(vA2 + 1568), acc, 0, 0, 0);
            acc = __builtin_amdgcn_mfma_f32_16x16x32_bf16(bfr[8],  *(const short8*)(vA2 + 3136), acc, 0, 0, 0);
            acc = __builtin_amdgcn_mfma_f32_16x16x32_bf16(bfr[9],  *(const short8*)(vB0),        acc, 0, 0, 0);
            acc = __builtin_amdgcn_mfma_f32_16x16x32_bf16(bfr[10], *(const short8*)(vB1),        acc, 0, 0, 0);
            acc = __builtin_amdgcn_mfma_f32_16x16x32_bf16(bfr[11], *(const short8*)(vB2),        acc, 0, 0, 0);
            acc = __builtin_amdgcn_mfma_f32_16x16x32_bf16(bfr[12], *(const short8*)(vC),         acc, 0, 0, 0);
            acc = __builtin_amdgcn_mfma_f32_16x16x32_bf16(bfr[13], *(const short8*)(vD),         acc, 0, 0, 0);

            float lm = logMt[wv * 96 + j * 16 + mn];
            float* op = ob + (size_t)(4 * q) * VOX
                      + (((size_t)z * 96 + (y0 + wv)) * 96 + j * 16 + mn);
            #pragma unroll
            for (int t = 0; t < 4; ++t) {
                float e = fminf(fmaf(wa[t], lm, acc[t]), 88.0f);
                op[(size_t)t * VOX] = __expf(e);
            }
        }
        __syncthreads();
        if (st) write_plane(z + 2);
    }
}

extern "C" void kernel_launch(void* const* d_in, const int* in_sizes, int n_in,
                              void* d_out, int out_size, void* d_ws, size_t ws_size,
                              hipStream_t stream) {
    const float* x = (const float*)d_in[0];
    const float* w = (const float*)d_in[1];
    float* out  = (float*)d_out;
    short* w3   = (short*)d_ws;                          // 16*448 bf16 = 14336 B
    float* wadj = (float*)((char*)d_ws + 14336);         // 16 floats
    short* lgx  = (short*)((char*)d_ws + 16384);         // logx scratch

    const size_t lx_full = (size_t)2 * VOX * 16 * 2;     // 56.6 MB (both batches)
    const size_t lx_half = (size_t)VOX * 16 * 2;         // 28.3 MB (one batch)

    hipLaunchKernelGGL(mvc_reorg, dim3(28), dim3(256), 0, stream, w, w3, wadj);

    if (ws_size >= 16384 + lx_full) {
        // Full path: one log pass (both batches), one conv pass.
        hipLaunchKernelGGL(mvc_log,  dim3(6912), dim3(256), 0, stream, x, lgx);
        hipLaunchKernelGGL(mvc_conv, dim3(768),  dim3(256), 0, stream, lgx, w3, wadj, out);
    } else if (ws_size >= 16384 + lx_half) {
        // Per-batch path: half-size scratch, serialized batches.
        for (int b = 0; b < 2; ++b) {
            hipLaunchKernelGGL(mvc_log,  dim3(3456), dim3(256), 0, stream,
                               x + (size_t)b * 16 * VOX, lgx);
            hipLaunchKernelGGL(mvc_conv, dim3(384),  dim3(256), 0, stream,
                               lgx, w3, wadj, out + (size_t)b * 16 * VOX);
        }
    } else {
        // Fallback: harness-verified fused kernel (16 KB workspace only).
        hipLaunchKernelGGL(mvc_main, dim3(768), dim3(256), 0, stream, x, w3, wadj, out);
    }
}

// Round 3
// 237.354 us; speedup vs baseline: 1.2197x; 1.0226x over previous
//
#include <hip/hip_runtime.h>

// MVC log-domain 3D conv.
// Preferred path (needs ~56.6 MB workspace):
//   K1 (mvc_logr): logx[b][voxel][ci] = bf16(log x)  (+ 28 tail blocks do weight reorg)
//   K2 (mvc_conv): implicit-GEMM conv on MFMA, staging via global_load_lds,
//                  4-slice rolling z buffer, counted-vmcnt raw-barrier loop:
//                  s_waitcnt vmcnt(12) keeps the 12 epilogue stores in flight and
//                  only waits for the 3 staging gll (vmcnt retires in order).
//                  logM folded in as a 15th MFMA (A = 1/16 on the dx=1 k-slots of
//                  the center-tap B fragment) -> mean_ci logx(center) in fp32.
// Fallback path (16 KB workspace): previous harness-verified fused kernel (mvc_main).
//
// K2 geometry: TY=2 output rows, full-x 96, ZC=12 planes/block.
//   LDS = 4 slices x 4 rows x 98 cols x 16ci bf16 (12544 B) + 1 KB trash = 51200 B
//   -> 3 blocks/CU, 12 waves/CU.  Grid 768 = 2b x 8zch x 48yt = exactly 3/CU.

#define VOX  884736            // 96^3
#define SLX  98                // 1 + 96 + 1 pad cols
#define ROWS (SLX * 16)        // 1568 shorts per LDS row
#define SROWS 4                // rows per slice (TY + 2 halo)
#define SSs  (SROWS * ROWS)    // 6272 shorts per slice
#define SSb  (SSs * 2)         // 12544 bytes per slice
#define NSL  4
#define TY   2
#define ZC   12

typedef __attribute__((ext_vector_type(8))) short short8;
typedef __attribute__((ext_vector_type(4))) float f32x4;

__device__ __forceinline__ unsigned short f2bf_rne(float f) {
    unsigned u = __float_as_uint(f);
    u += 0x7fff + ((u >> 16) & 1);
    return (unsigned short)(u >> 16);
}
__device__ __forceinline__ float bf2f(short s) {
    return __uint_as_float(((unsigned)(unsigned short)s) << 16);
}

// ---------------------------------------------------------------------------
// Weight reorg body (device): w3[cout][k=448] MFMA A-order, wadj = 1-sum(w).
// ---------------------------------------------------------------------------
__device__ __forceinline__ void reorg_body(int i, const float* __restrict__ w,
                                           short* __restrict__ w3,
                                           float* __restrict__ wadj) {
    if (i < 16 * 448) {
        int n = i / 448, k = i % 448;
        int p = k >> 5, q = (k >> 3) & 3, j = k & 7;
        int qhi = q >> 1, ci = (q & 1) * 8 + j;
        int tap;
        bool valid = true;
        if (p < 9)        tap = (p / 3) * 9 + (p % 3) * 3 + qhi;
        else if (p < 12)  tap = (p - 9) * 9 + qhi * 3 + 2;
        else if (p == 12) tap = qhi * 9 + 8;
        else { tap = 26; valid = (qhi == 0); }
        float v = valid ? w[n * 432 + tap * 16 + ci] : 0.0f;
        w3[i] = (short)f2bf_rne(v);
    }
    if (i < 16) {
        const float* pw = w + i * 432;
        float s = 0.0f;
        for (int t = 0; t < 432; ++t) s += pw[t];
        wadj[i] = 1.0f - s;
    }
}

__global__ void mvc_reorg(const float* __restrict__ w,
                          short* __restrict__ w3,
                          float* __restrict__ wadj) {
    reorg_body(blockIdx.x * 256 + threadIdx.x, w, w3, wadj);
}

// ---------------------------------------------------------------------------
// K1: log transform + transpose to [b][voxel][ci] bf16 (32 B records).
// Blocks >= 6912 run the weight reorg instead (merged dispatch).
// ---------------------------------------------------------------------------
__global__ void __launch_bounds__(256)
mvc_logr(const float* __restrict__ x, short* __restrict__ lx,
         const float* __restrict__ w, short* __restrict__ w3,
         float* __restrict__ wadj) {
    const int id = blockIdx.x;
    if (id >= 6912) {
        reorg_body((id - 6912) * 256 + threadIdx.x, w, w3, wadj);
        return;
    }
    const int b = id / 3456;
    const size_t v = (size_t)(id - b * 3456) * 256 + threadIdx.x;
    const float* xb = x + (size_t)b * 16 * VOX + v;
    unsigned rbuf[8];
    #pragma unroll
    for (int c = 0; c < 8; ++c) {
        unsigned lo = f2bf_rne(__logf(xb[(size_t)(2 * c) * VOX]));
        unsigned hi = f2bf_rne(__logf(xb[(size_t)(2 * c + 1) * VOX]));
        rbuf[c] = lo | (hi << 16);
    }
    unsigned* dst = (unsigned*)(lx + ((size_t)b * VOX + v) * 16);
    *(uint4*)dst       = make_uint4(rbuf[0], rbuf[1], rbuf[2], rbuf[3]);
    *(uint4*)(dst + 4) = make_uint4(rbuf[4], rbuf[5], rbuf[6], rbuf[7]);
}

// Plain log kernel (per-batch fallback path).
__global__ void __launch_bounds__(256)
mvc_log(const float* __restrict__ x, short* __restrict__ lx) {
    const int id = blockIdx.x;
    const int b = id / 3456;
    const size_t v = (size_t)(id - b * 3456) * 256 + threadIdx.x;
    const float* xb = x + (size_t)b * 16 * VOX + v;
    unsigned rbuf[8];
    #pragma unroll
    for (int c = 0; c < 8; ++c) {
        unsigned lo = f2bf_rne(__logf(xb[(size_t)(2 * c) * VOX]));
        unsigned hi = f2bf_rne(__logf(xb[(size_t)(2 * c + 1) * VOX]));
        rbuf[c] = lo | (hi << 16);
    }
    unsigned* dst = (unsigned*)(lx + ((size_t)b * VOX + v) * 16);
    *(uint4*)dst       = make_uint4(rbuf[0], rbuf[1], rbuf[2], rbuf[3]);
    *(uint4*)(dst + 4) = make_uint4(rbuf[4], rbuf[5], rbuf[6], rbuf[7]);
}

// ---------------------------------------------------------------------------
// K2: conv + exp.  LDS 51200 B -> 3 blocks/CU.  Grid nb*384.
// ---------------------------------------------------------------------------
__global__ void __launch_bounds__(256, 3)
mvc_conv(const short* __restrict__ lx,
         const short* __restrict__ w3,
         const float* __restrict__ wadj,
         float* __restrict__ out) {
    __shared__ __align__(16) short tile[NSL * SSs + 512];   // + 1 KB trash

    const int tid  = threadIdx.x;
    const int lane = tid & 63;
    const int wv   = tid >> 6;
    const int mn   = lane & 15;
    const int q    = lane >> 4;
    const int qlo  = q & 1;
    const int qhi  = q >> 1;

    // XCD swizzle: 6 consecutive y-tiles per XCD (y-halo L2 capture).
    int id  = blockIdx.x;
    int xcd = id & 7, g = id >> 3;
    int yt  = xcd * 6 + g % 6;            // 0..47
    int rr  = g / 6;
    int zch = rr % 8, b = rr / 8;
    const int y0 = yt * TY;
    const int z0 = zch * ZC;

    const short* lxb = lx + (size_t)b * VOX * 16;
    float* ob = out + (size_t)b * 16 * VOX;

    // loop-invariant: weight A-fragments + wadj + the logM "ones" fragment
    short8 bfr[14];
    #pragma unroll
    for (int p = 0; p < 14; ++p)
        bfr[p] = *(const short8*)(w3 + mn * 448 + p * 32 + q * 8);
    const float4 wv4 = *(const float4*)(wadj + 4 * q);
    const float wa[4] = {wv4.x, wv4.y, wv4.z, wv4.w};
    const short oc = qhi ? (short)0x3D80 : (short)0;    // 1/16 bf16 on dx=1 k-slots
    const short8 aones = {oc, oc, oc, oc, oc, oc, oc, oc};

    // ---- staging: one wave per slice row, 3x 1024 B global_load_lds chunks ----
    auto stage = [&](int zp) {            // 0 <= zp < 96 guaranteed by caller
        const int sl = zp & 3;
        const int gy = y0 - 1 + wv;
        const bool vr = (unsigned)gy < 96u;
        const int gyc = vr ? gy : 0;
        const short* gsrc = lxb + (size_t)(zp * 9216 + gyc * 96) * 16 + lane * 8;
        short* lrow = tile + sl * SSs + (wv * SLX + 1) * 16;
        short* ltr  = tile + NSL * SSs;   // trash sink for out-of-range rows
        #pragma unroll
        for (int k = 0; k < 3; ++k) {
            short* dst = vr ? (lrow + k * 512) : ltr;
            __builtin_amdgcn_global_load_lds(
                (const __attribute__((address_space(1))) unsigned int*)(const void*)(gsrc + k * 512),
                (__attribute__((address_space(3))) unsigned int*)(void*)dst,
                16, 0, 0);
        }
    };
    auto zero_slice = [&](int sl) {       // 12544 B = 784 x 16 B
        #pragma unroll
        for (int i = 0; i < 4; ++i) {
            int c = tid + i * 256;
            if (c < 784)
                *(f32x4*)((char*)tile + sl * SSb + c * 16) = (f32x4){0.f, 0.f, 0.f, 0.f};
        }
    };

    // ---- prologue: zero pads / boundary rows, stage planes z0-1, z0, z0+1 ----
    if (tid < 64) {                       // pad cols 0 and 97, all slices/rows
        int s = tid >> 4, rest = tid & 15;
        int row = rest >> 2, side = (rest >> 1) & 1, half = tid & 1;
        *(f32x4*)((char*)tile + s * SSb + (row * SLX + side * 97) * 32 + half * 16)
            = (f32x4){0.f, 0.f, 0.f, 0.f};
    }
    if (yt == 0 || yt == 47) {            // fully out-of-range y row stays zero
        int row = (yt == 0) ? 0 : 3;
        #pragma unroll
        for (int s = 0; s < 4; ++s)
            if (tid < 196)
                *(f32x4*)((char*)tile + s * SSb + row * 3136 + tid * 16)
                    = (f32x4){0.f, 0.f, 0.f, 0.f};
    }
    if (z0 == 0) zero_slice(3); else stage(z0 - 1);
    stage(z0);
    stage(z0 + 1);
    __syncthreads();   // full drain (vmcnt+lgkm) + barrier: 3 planes ready

    // ---- rolling z-march: counted-vmcnt raw-barrier loop (T4 pattern) ----
    // Per iteration: issue stage(z+2) first (latency hidden under compute), then
    // compute plane z (45 ds_read_b128 + 45 MFMA + epilogue, 12 stores), then
    // s_waitcnt vmcnt(12): waits ONLY the 3 gll (older), leaves stores in flight.
    #pragma unroll 1
    for (int zi = 0; zi < ZC; ++zi) {
        const int z = z0 + zi;
        if (zi < ZC - 1) {
            const int zp = z + 2;
            if (zp < 96) stage(zp);       // into slice (z+2)&3 -- not read this iter
            else         zero_slice(zp & 3);
        }
        __builtin_amdgcn_sched_barrier(0);

        const int B0 = ((z + 3) & 3) * SSs;   // plane z-1
        const int B1 = (z & 3) * SSs;         // plane z
        const int B2 = ((z + 1) & 3) * SSs;   // plane z+1
        const int r  = wv >> 1;               // wave's output y row (0/1)
        const int xh = wv & 1;                // wave's x half
        const int Lb = mn * 16 + qlo * 8 + r * ROWS + qhi * 16;

        #pragma unroll
        for (int jj = 0; jj < 3; ++jj) {
            const int j = xh * 3 + jj;
            const short* vA0 = tile + (Lb + j * 256 + B0);
            const short* vA1 = tile + (Lb + j * 256 + B1);
            const short* vA2 = tile + (Lb + j * 256 + B2);
            const short* vB0 = vA0 + 32 + qhi * 1552;      // dx=2, dy=qhi fold
            const short* vB1 = vA1 + 32 + qhi * 1552;
            const short* vB2 = vA2 + 32 + qhi * 1552;
            const short* vD  = vB2 + (3136 - qhi * 1584);  // dz2,dy2,dx2 (both halves)
            const short* vC  = vD - B2 + (qhi ? B1 : B0);  // dz=qhi, dy2, dx2

            f32x4 acc = {0.f, 0.f, 0.f, 0.f};
            acc = __builtin_amdgcn_mfma_f32_16x16x32_bf16(bfr[0],  *(const short8*)(vA0),        acc, 0, 0, 0);
            acc = __builtin_amdgcn_mfma_f32_16x16x32_bf16(bfr[1],  *(const short8*)(vA0 + 1568), acc, 0, 0, 0);
            acc = __builtin_amdgcn_mfma_f32_16x16x32_bf16(bfr[2],  *(const short8*)(vA0 + 3136), acc, 0, 0, 0);
            acc = __builtin_amdgcn_mfma_f32_16x16x32_bf16(bfr[3],  *(const short8*)(vA1),        acc, 0, 0, 0);
            acc = __builtin_amdgcn_mfma_f32_16x16x32_bf16(bfr[4],  *(const short8*)(vA1 + 1568), acc, 0, 0, 0);
            acc = __builtin_amdgcn_mfma_f32_16x16x32_bf16(bfr[5],  *(const short8*)(vA1 + 3136), acc, 0, 0, 0);
            acc = __builtin_amdgcn_mfma_f32_16x16x32_bf16(bfr[6],  *(const short8*)(vA2),        acc, 0, 0, 0);
            acc = __builtin_amdgcn_mfma_f32_16x16x32_bf16(bfr[7],  *(const short8*)(vA2 + 1568), acc, 0, 0, 0);
            acc = __builtin_amdgcn_mfma_f32_16x16x32_bf16(bfr[8],  *(const short8*)(vA2 + 3136), acc, 0, 0, 0);
            acc = __builtin_amdgcn_mfma_f32_16x16x32_bf16(bfr[9],  *(const short8*)(vB0),        acc, 0, 0, 0);
            acc = __builtin_amdgcn_mfma_f32_16x16x32_bf16(bfr[10], *(const short8*)(vB1),        acc, 0, 0, 0);
            acc = __builtin_amdgcn_mfma_f32_16x16x32_bf16(bfr[11], *(const short8*)(vB2),        acc, 0, 0, 0);
            acc = __builtin_amdgcn_mfma_f32_16x16x32_bf16(bfr[12], *(const short8*)(vC),         acc, 0, 0, 0);
            acc = __builtin_amdgcn_mfma_f32_16x16x32_bf16(bfr[13], *(const short8*)(vD),         acc, 0, 0, 0);

            // logM via MFMA: mean_ci of center tap (reuses the vA1+1568 ds_read)
            f32x4 am = __builtin_amdgcn_mfma_f32_16x16x32_bf16(
                aones, *(const short8*)(vA1 + 1568), (f32x4){0.f, 0.f, 0.f, 0.f}, 0, 0, 0);
            const float lm = am[0];

            // epilogue: D row m = 4q+t = cout, col n = mn = x -> 64 B-run stores
            float* op = ob + (size_t)(4 * q) * VOX
                      + (((size_t)z * 96 + (y0 + r)) * 96 + j * 16 + mn);
            #pragma unroll
            for (int t = 0; t < 4; ++t) {
                float e = fminf(fmaf(wa[t], lm, acc[t]), 88.0f);
                op[(size_t)t * VOX] = __expf(e);
            }
        }

        if (zi < ZC - 1) {
            // Wait for this iter's 3 gll (oldest outstanding after prior iters'
            // stores retired); the 12 stores just issued may remain in flight.
            asm volatile("s_waitcnt vmcnt(12) lgkmcnt(0)" ::: "memory");
            __builtin_amdgcn_s_barrier();
            __builtin_amdgcn_sched_barrier(0);
        }
    }
}

// ---------------------------------------------------------------------------
// Fallback: previous harness-verified fused kernel (289.8 us), 16 KB workspace.
// ---------------------------------------------------------------------------
#define FSLY  6
#define FROWS (SLX * 16)
#define FSS   (FSLY * FROWS)
#define FTY   4
#define FZC   6

__global__ void __launch_bounds__(256, 2)
mvc_main(const float* __restrict__ x,
         const short* __restrict__ w3,
         const float* __restrict__ wadj,
         float* __restrict__ out) {
    __shared__ __align__(16) short tile[3 * FSS];
    __shared__ float logMt[FTY * 96];

    const int tid  = threadIdx.x;
    const int lane = tid & 63;
    const int wv   = tid >> 6;
    const int mn   = lane & 15;
    const int q    = lane >> 4;
    const int qlo  = q & 1;
    const int qhi  = q >> 1;

    int id  = blockIdx.x;
    int xcd = id & 7, g = id >> 3;
    int yt  = xcd * 3 + g % 3;
    int rr  = g / 3;
    int zch = rr & 15, b = rr >> 4;
    const int y0 = yt * FTY;
    const int z0 = zch * FZC;

    const float* xb = x + (size_t)b * 16 * VOX;
    float* ob = out + (size_t)b * 16 * VOX;

    short8 bfr[14];
    #pragma unroll
    for (int p = 0; p < 14; ++p)
        bfr[p] = *(const short8*)(w3 + mn * 448 + p * 32 + q * 8);
    const float4 wv4 = *(const float4*)(wadj + 4 * q);
    const float wa[4] = {wv4.x, wv4.y, wv4.z, wv4.w};

    if (tid < 288) {
        int d = tid & 7, vv = tid >> 3;
        int bu = vv / 12, rv = vv % 12;
        int row = rv >> 1, side = rv & 1;
        ((unsigned*)tile)[bu * (FSS / 2) + (row * SLX + side * 97) * 8 + d] = 0u;
    }

    float2 h[5][4];

    auto load_plane = [&](int zp) {
        bool zin = (unsigned)zp < 96u;
        #pragma unroll
        for (int it = 0; it < 5; ++it) {
            if (it == 4 && tid >= 128) break;
            int slot = tid + it * 256;
            int cq = slot & 3;
            int t  = slot >> 2;
            int xp = t % 48;
            int y  = t / 48;
            int gy = y0 + y - 1;
            bool inb = zin && ((unsigned)gy < 96u);
            const float* p0 = xb + (size_t)(4 * cq) * VOX
                            + ((zp * 96 + gy) * 96 + 2 * xp);
            h[it][0] = inb ? *(const float2*)(p0)            : make_float2(1.f, 1.f);
            h[it][1] = inb ? *(const float2*)(p0 + VOX)      : make_float2(1.f, 1.f);
            h[it][2] = inb ? *(const float2*)(p0 + 2 * VOX)  : make_float2(1.f, 1.f);
            h[it][3] = inb ? *(const float2*)(p0 + 3 * VOX)  : make_float2(1.f, 1.f);
        }
    };
    auto write_plane = [&](int zp) {
        short* sb = tile + ((zp + 3) % 3) * FSS;
        #pragma unroll
        for (int it = 0; it < 5; ++it) {
            if (it == 4 && tid >= 128) break;
            int slot = tid + it * 256;
            int cq = slot & 3;
            int t  = slot >> 2;
            int xp = t % 48;
            int y  = t / 48;
            unsigned a0 = f2bf_rne(__logf(h[it][0].x)), a1 = f2bf_rne(__logf(h[it][1].x));
            unsigned a2 = f2bf_rne(__logf(h[it][2].x)), a3 = f2bf_rne(__logf(h[it][3].x));
            unsigned c0 = f2bf_rne(__logf(h[it][0].y)), c1 = f2bf_rne(__logf(h[it][1].y));
            unsigned c2 = f2bf_rne(__logf(h[it][2].y)), c3 = f2bf_rne(__logf(h[it][3].y));
            unsigned* dst = (unsigned*)(sb + (y * SLX + 1 + 2 * xp) * 16 + 4 * cq);
            *(uint2*)(dst)     = make_uint2(a0 | (a1 << 16), a2 | (a3 << 16));
            *(uint2*)(dst + 8) = make_uint2(c0 | (c1 << 16), c2 | (c3 << 16));
        }
    };
    auto do_logM = [&](int z) {
        const short* cb = tile + (z % 3) * FSS;
        #pragma unroll
        for (int it = 0; it < 2; ++it) {
            if (it == 1 && tid >= 128) break;
            int v = tid + it * 256;
            int xx = v % 96, yy = v / 96;
            const short* p = cb + ((yy + 1) * SLX + (xx + 1)) * 16;
            short8 h0 = *(const short8*)p;
            short8 h1 = *(const short8*)(p + 8);
            float s = 0.f;
            #pragma unroll
            for (int c = 0; c < 8; ++c) s += bf2f(h0[c]) + bf2f(h1[c]);
            logMt[v] = s * 0.0625f;
        }
    };

    load_plane(z0 - 1); write_plane(z0 - 1);
    load_plane(z0);     write_plane(z0);
    load_plane(z0 + 1); write_plane(z0 + 1);
    __syncthreads();

    for (int zi = 0; zi < FZC; ++zi) {
        const int z = z0 + zi;
        const bool st = (zi < FZC - 1);
        if (st) load_plane(z + 2);
        do_logM(z);
        __syncthreads();

        const int B0 = ((z + 2) % 3) * FSS;
        const int B1 = (z % 3) * FSS;
        const int B2 = ((z + 1) % 3) * FSS;
        const int Lb = mn * 16 + qlo * 8 + wv * FROWS + qhi * 16;

        #pragma unroll
        for (int j = 0; j < 6; ++j) {
            const short* vA0 = tile + (Lb + j * 256 + B0);
            const short* vA1 = tile + (Lb + j * 256 + B1);
            const short* vA2 = tile + (Lb + j * 256 + B2);
            const short* vB0 = vA0 + 32 + qhi * 1552;
            const short* vB1 = vA1 + 32 + qhi * 1552;
            const short* vB2 = vA2 + 32 + qhi * 1552;
            const short* vD  = vB2 + (3136 - qhi * 1584);
            const short* vC  = vD - B2 + (qhi ? B1 : B0);

            f32x4 acc = {0.f, 0.f, 0.f, 0.f};
            acc = __builtin_amdgcn_mfma_f32_16x16x32_bf16(bfr[0],  *(const short8*)(vA0),        acc, 0, 0, 0);
            acc = __builtin_amdgcn_mfma_f32_16x16x32_bf16(bfr[1],  *(const short8*)(vA0 + 1568), acc, 0, 0, 0);
            acc = __builtin_amdgcn_mfma_f32_16x16x32_bf16(bfr[2],  *(const short8*)(vA0 + 3136), acc, 0, 0, 0);
            acc = __builtin_amdgcn_mfma_f32_16x16x32_bf16(bfr[3],  *(const short8*)(vA1),        acc, 0, 0, 0);
            acc = __builtin_amdgcn_mfma_f32_16x16x32_bf16(bfr[4],  *(const short8*)(vA1 + 1568), acc, 0, 0, 0);
            acc = __builtin_amdgcn_mfma_f32_16x16x32_bf16(bfr[5],  *(const short8*)(vA1 + 3136), acc, 0, 0, 0);
            acc = __builtin_amdgcn_mfma_f32_16x16x32_bf16(bfr[6],  *(const short8*)(vA2),        acc, 0, 0, 0);
            acc = __builtin_amdgcn_mfma_f32_16x16x32_bf16(bfr[7],  *(const short8*)(vA2 + 1568), acc, 0, 0, 0);
            acc = __builtin_amdgcn_mfma_f32_16x16x32_bf16(bfr[8],  *(const short8*)(vA2 + 3136), acc, 0, 0, 0);
            acc = __builtin_amdgcn_mfma_f32_16x16x32_bf16(bfr[9],  *(const short8*)(vB0),        acc, 0, 0, 0);
            acc = __builtin_amdgcn_mfma_f32_16x16x32_bf16(bfr[10], *(const short8*)(vB1),        acc, 0, 0, 0);
            acc = __builtin_amdgcn_mfma_f32_16x16x32_bf16(bfr[11], *(const short8*)(vB2),        acc, 0, 0, 0);
            acc = __builtin_amdgcn_mfma_f32_16x16x32_bf16(bfr[12], *(const short8*)(vC),         acc, 0, 0, 0);
            acc = __builtin_amdgcn_mfma_f32_16x16x32_bf16(bfr[13], *(const short8*)(vD),         acc, 0, 0, 0);

            float lm = logMt[wv * 96 + j * 16 + mn];
            float* op = ob + (size_t)(4 * q) * VOX
                      + (((size_t)z * 96 + (y0 + wv)) * 96 + j * 16 + mn);
            #pragma unroll
            for (int t = 0; t < 4; ++t) {
                float e = fminf(fmaf(wa[t], lm, acc[t]), 88.0f);
                op[(size_t)t * VOX] = __expf(e);
            }
        }
        __syncthreads();
        if (st) write_plane(z + 2);
    }
}

extern "C" void kernel_launch(void* const* d_in, const int* in_sizes, int n_in,
                              void* d_out, int out_size, void* d_ws, size_t ws_size,
                              hipStream_t stream) {
    const float* x = (const float*)d_in[0];
    const float* w = (const float*)d_in[1];
    float* out  = (float*)d_out;
    short* w3   = (short*)d_ws;                          // 16*448 bf16 = 14336 B
    float* wadj = (float*)((char*)d_ws + 14336);         // 16 floats
    short* lgx  = (short*)((char*)d_ws + 16384);         // logx scratch

    const size_t lx_full = (size_t)2 * VOX * 16 * 2;     // 56.6 MB (both batches)
    const size_t lx_half = (size_t)VOX * 16 * 2;         // 28.3 MB (one batch)

    if (ws_size >= 16384 + lx_full) {
        // Full path: merged log+reorg pass, then one conv pass.
        hipLaunchKernelGGL(mvc_logr, dim3(6940), dim3(256), 0, stream,
                           x, lgx, w, w3, wadj);
        hipLaunchKernelGGL(mvc_conv, dim3(768),  dim3(256), 0, stream,
                           lgx, w3, wadj, out);
    } else if (ws_size >= 16384 + lx_half) {
        // Per-batch path: half-size scratch, serialized batches.
        hipLaunchKernelGGL(mvc_reorg, dim3(28), dim3(256), 0, stream, w, w3, wadj);
        for (int b = 0; b < 2; ++b) {
            hipLaunchKernelGGL(mvc_log,  dim3(3456), dim3(256), 0, stream,
                               x + (size_t)b * 16 * VOX, lgx);
            hipLaunchKernelGGL(mvc_conv, dim3(384),  dim3(256), 0, stream,
                               lgx, w3, wadj, out + (size_t)b * 16 * VOX);
        }
    } else {
        // Fallback: harness-verified fused kernel (16 KB workspace only).
        hipLaunchKernelGGL(mvc_reorg, dim3(28), dim3(256), 0, stream, w, w3, wadj);
        hipLaunchKernelGGL(mvc_main, dim3(768), dim3(256), 0, stream, x, w3, wadj, out);
    }
}

// Round 4
// 235.517 us; speedup vs baseline: 1.2292x; 1.0078x over previous
//
#include <hip/hip_runtime.h>

// MVC log-domain 3D conv.
// Preferred path (needs ~56.6 MB workspace):
//   K1 (mvc_logr): logx2[b][voxel][ci] = bf16(log2 x)  (+ 28 tail blocks do weight reorg)
//   K2 (mvc_conv): implicit-GEMM conv on MFMA, staging via global_load_lds,
//                  4-slice rolling z buffer, counted-vmcnt raw-barrier loop
//                  (vmcnt(15): staged plane's gll only needs to land by the SECOND
//                  barrier after issue -- it is read at iter+2).
//                  dz register reuse: the per-j A-set (intra-slice offsets
//                  +0/+1568/+3136) is held in registers for one iteration, so the
//                  vA1-set is a register reuse of last iter's vA2-set reads
//                  (14 -> 11 ds_read_b128 per j, -21% LDS traffic).
//                  logM folded in as a 15th MFMA (A = 1/16 on the dx=1 k-slots of
//                  the held center fragment) -> mean_ci log2x(center) in fp32.
//                  Whole pipeline in log2 domain: epilogue is v_exp_f32 directly.
// Fallback path (16 KB workspace): previous harness-verified fused kernel (mvc_main).
//
// K2 geometry: TY=2 output rows, full-x 96, ZC=12 planes/block.
//   LDS = 4 slices x 4 rows x 98 cols x 16ci bf16 (12544 B) + 1 KB trash = 51200 B
//   -> 3 blocks/CU, 12 waves/CU.  Grid 768 = 2b x 8zch x 48yt = exactly 3/CU.

#define VOX  884736            // 96^3
#define SLX  98                // 1 + 96 + 1 pad cols
#define ROWS (SLX * 16)        // 1568 shorts per LDS row
#define SROWS 4                // rows per slice (TY + 2 halo)
#define SSs  (SROWS * ROWS)    // 6272 shorts per slice
#define SSb  (SSs * 2)         // 12544 bytes per slice
#define NSL  4
#define TY   2
#define ZC   12

typedef __attribute__((ext_vector_type(8))) short short8;
typedef __attribute__((ext_vector_type(4))) float f32x4;

__device__ __forceinline__ unsigned short f2bf_rne(float f) {
    unsigned u = __float_as_uint(f);
    u += 0x7fff + ((u >> 16) & 1);
    return (unsigned short)(u >> 16);
}
__device__ __forceinline__ float bf2f(short s) {
    return __uint_as_float(((unsigned)(unsigned short)s) << 16);
}

// ---------------------------------------------------------------------------
// Weight reorg body (device): w3[cout][k=448] MFMA A-order, wadj = 1-sum(w).
// ---------------------------------------------------------------------------
__device__ __forceinline__ void reorg_body(int i, const float* __restrict__ w,
                                           short* __restrict__ w3,
                                           float* __restrict__ wadj) {
    if (i < 16 * 448) {
        int n = i / 448, k = i % 448;
        int p = k >> 5, q = (k >> 3) & 3, j = k & 7;
        int qhi = q >> 1, ci = (q & 1) * 8 + j;
        int tap;
        bool valid = true;
        if (p < 9)        tap = (p / 3) * 9 + (p % 3) * 3 + qhi;
        else if (p < 12)  tap = (p - 9) * 9 + qhi * 3 + 2;
        else if (p == 12) tap = qhi * 9 + 8;
        else { tap = 26; valid = (qhi == 0); }
        float v = valid ? w[n * 432 + tap * 16 + ci] : 0.0f;
        w3[i] = (short)f2bf_rne(v);
    }
    if (i < 16) {
        const float* pw = w + i * 432;
        float s = 0.0f;
        for (int t = 0; t < 432; ++t) s += pw[t];
        wadj[i] = 1.0f - s;
    }
}

__global__ void mvc_reorg(const float* __restrict__ w,
                          short* __restrict__ w3,
                          float* __restrict__ wadj) {
    reorg_body(blockIdx.x * 256 + threadIdx.x, w, w3, wadj);
}

// ---------------------------------------------------------------------------
// K1: log2 transform + transpose to [b][voxel][ci] bf16 (32 B records).
// Blocks >= 6912 run the weight reorg instead (merged dispatch).
// ---------------------------------------------------------------------------
__global__ void __launch_bounds__(256)
mvc_logr(const float* __restrict__ x, short* __restrict__ lx,
         const float* __restrict__ w, short* __restrict__ w3,
         float* __restrict__ wadj) {
    const int id = blockIdx.x;
    if (id >= 6912) {
        reorg_body((id - 6912) * 256 + threadIdx.x, w, w3, wadj);
        return;
    }
    const int b = id / 3456;
    const size_t v = (size_t)(id - b * 3456) * 256 + threadIdx.x;
    const float* xb = x + (size_t)b * 16 * VOX + v;
    unsigned rbuf[8];
    #pragma unroll
    for (int c = 0; c < 8; ++c) {
        unsigned lo = f2bf_rne(__log2f(xb[(size_t)(2 * c) * VOX]));
        unsigned hi = f2bf_rne(__log2f(xb[(size_t)(2 * c + 1) * VOX]));
        rbuf[c] = lo | (hi << 16);
    }
    unsigned* dst = (unsigned*)(lx + ((size_t)b * VOX + v) * 16);
    *(uint4*)dst       = make_uint4(rbuf[0], rbuf[1], rbuf[2], rbuf[3]);
    *(uint4*)(dst + 4) = make_uint4(rbuf[4], rbuf[5], rbuf[6], rbuf[7]);
}

// Plain log2 kernel (per-batch fallback path).
__global__ void __launch_bounds__(256)
mvc_log(const float* __restrict__ x, short* __restrict__ lx) {
    const int id = blockIdx.x;
    const int b = id / 3456;
    const size_t v = (size_t)(id - b * 3456) * 256 + threadIdx.x;
    const float* xb = x + (size_t)b * 16 * VOX + v;
    unsigned rbuf[8];
    #pragma unroll
    for (int c = 0; c < 8; ++c) {
        unsigned lo = f2bf_rne(__log2f(xb[(size_t)(2 * c) * VOX]));
        unsigned hi = f2bf_rne(__log2f(xb[(size_t)(2 * c + 1) * VOX]));
        rbuf[c] = lo | (hi << 16);
    }
    unsigned* dst = (unsigned*)(lx + ((size_t)b * VOX + v) * 16);
    *(uint4*)dst       = make_uint4(rbuf[0], rbuf[1], rbuf[2], rbuf[3]);
    *(uint4*)(dst + 4) = make_uint4(rbuf[4], rbuf[5], rbuf[6], rbuf[7]);
}

// ---------------------------------------------------------------------------
// K2: conv + exp2.  LDS 51200 B -> 3 blocks/CU.  Grid nb*384.
// ---------------------------------------------------------------------------
__global__ void __launch_bounds__(256, 3)
mvc_conv(const short* __restrict__ lx,
         const short* __restrict__ w3,
         const float* __restrict__ wadj,
         float* __restrict__ out) {
    __shared__ __align__(16) short tile[NSL * SSs + 512];   // + 1 KB trash

    const int tid  = threadIdx.x;
    const int lane = tid & 63;
    const int wv   = tid >> 6;
    const int mn   = lane & 15;
    const int q    = lane >> 4;
    const int qlo  = q & 1;
    const int qhi  = q >> 1;

    // XCD swizzle: 6 consecutive y-tiles per XCD (y-halo L2 capture).
    int id  = blockIdx.x;
    int xcd = id & 7, g = id >> 3;
    int yt  = xcd * 6 + g % 6;            // 0..47
    int rr  = g / 6;
    int zch = rr % 8, b = rr / 8;
    const int y0 = yt * TY;
    const int z0 = zch * ZC;

    const short* lxb = lx + (size_t)b * VOX * 16;
    float* ob = out + (size_t)b * 16 * VOX;

    // loop-invariant: weight A-fragments + wadj + the logM "ones" fragment
    short8 bfr[14];
    #pragma unroll
    for (int p = 0; p < 14; ++p)
        bfr[p] = *(const short8*)(w3 + mn * 448 + p * 32 + q * 8);
    const float4 wv4 = *(const float4*)(wadj + 4 * q);
    const float wa[4] = {wv4.x, wv4.y, wv4.z, wv4.w};
    const short oc = qhi ? (short)0x3D80 : (short)0;    // 1/16 bf16 on dx=1 k-slots
    const short8 aones = {oc, oc, oc, oc, oc, oc, oc, oc};

    // ---- staging: one wave per slice row, 3x 1024 B global_load_lds chunks ----
    auto stage = [&](int zp) {            // 0 <= zp < 96 guaranteed by caller
        const int sl = zp & 3;
        const int gy = y0 - 1 + wv;
        const bool vr = (unsigned)gy < 96u;
        const int gyc = vr ? gy : 0;
        const short* gsrc = lxb + (size_t)(zp * 9216 + gyc * 96) * 16 + lane * 8;
        short* lrow = tile + sl * SSs + (wv * SLX + 1) * 16;
        short* ltr  = tile + NSL * SSs;   // trash sink for out-of-range rows
        #pragma unroll
        for (int k = 0; k < 3; ++k) {
            short* dst = vr ? (lrow + k * 512) : ltr;
            __builtin_amdgcn_global_load_lds(
                (const __attribute__((address_space(1))) unsigned int*)(const void*)(gsrc + k * 512),
                (__attribute__((address_space(3))) unsigned int*)(void*)dst,
                16, 0, 0);
        }
    };
    auto zero_slice = [&](int sl) {       // 12544 B = 784 x 16 B
        #pragma unroll
        for (int i = 0; i < 4; ++i) {
            int c = tid + i * 256;
            if (c < 784)
                *(f32x4*)((char*)tile + sl * SSb + c * 16) = (f32x4){0.f, 0.f, 0.f, 0.f};
        }
    };

    // ---- prologue: zero pads / boundary rows, stage planes z0-1, z0, z0+1 ----
    if (tid < 64) {                       // pad cols 0 and 97, all slices/rows
        int s = tid >> 4, rest = tid & 15;
        int row = rest >> 2, side = (rest >> 1) & 1, half = tid & 1;
        *(f32x4*)((char*)tile + s * SSb + (row * SLX + side * 97) * 32 + half * 16)
            = (f32x4){0.f, 0.f, 0.f, 0.f};
    }
    if (yt == 0 || yt == 47) {            // fully out-of-range y row stays zero
        int row = (yt == 0) ? 0 : 3;
        #pragma unroll
        for (int s = 0; s < 4; ++s)
            if (tid < 196)
                *(f32x4*)((char*)tile + s * SSb + row * 3136 + tid * 16)
                    = (f32x4){0.f, 0.f, 0.f, 0.f};
    }
    if (z0 == 0) zero_slice(3); else stage(z0 - 1);
    stage(z0);
    stage(z0 + 1);
    __syncthreads();   // full drain (vmcnt+lgkm) + barrier: 3 planes ready

    const int r  = wv >> 1;               // wave's output y row (0/1)
    const int xh = wv & 1;                // wave's x half
    const int Lb = mn * 16 + qlo * 8 + r * ROWS + qhi * 16;

    // ---- dz register reuse: held A-set of plane z (consumed as vA1 this iter) ----
    // Initialized from plane z0's slice; refreshed each iter from the vA2 reads.
    short8 hA[3][3];
    {
        const int Bi = (z0 & 3) * SSs;
        #pragma unroll
        for (int jj = 0; jj < 3; ++jj) {
            const short* vI = tile + (Lb + (xh * 3 + jj) * 256 + Bi);
            hA[jj][0] = *(const short8*)(vI);
            hA[jj][1] = *(const short8*)(vI + 1568);
            hA[jj][2] = *(const short8*)(vI + 3136);
        }
    }

    // ---- rolling z-march: counted-vmcnt raw-barrier loop (T4 pattern) ----
    #pragma unroll 1
    for (int zi = 0; zi < ZC; ++zi) {
        const int z = z0 + zi;
        if (zi < ZC - 1) {
            const int zp = z + 2;
            if (zp < 96) stage(zp);       // into slice (z+2)&3 -- not read this iter
            else         zero_slice(zp & 3);
        }
        __builtin_amdgcn_sched_barrier(0);

        const int B0 = ((z + 3) & 3) * SSs;   // plane z-1
        const int B1 = (z & 3) * SSs;         // plane z
        const int B2 = ((z + 1) & 3) * SSs;   // plane z+1

        #pragma unroll
        for (int jj = 0; jj < 3; ++jj) {
            const int j = xh * 3 + jj;
            const short* vA0 = tile + (Lb + j * 256 + B0);
            const short* vA1 = tile + (Lb + j * 256 + B1);
            const short* vA2 = tile + (Lb + j * 256 + B2);
            const short* vB0 = vA0 + 32 + qhi * 1552;      // dx=2, dy=qhi fold
            const short* vB1 = vA1 + 32 + qhi * 1552;
            const short* vB2 = vA2 + 32 + qhi * 1552;
            const short* vD  = vB2 + (3136 - qhi * 1584);  // dz2,dy2,dx2 (both halves)
            const short* vC  = vD - B2 + (qhi ? B1 : B0);  // dz=qhi, dy2, dx2

            // fresh reads of the leading plane's A-set (become next iter's held set)
            short8 nA0 = *(const short8*)(vA2);
            short8 nA1 = *(const short8*)(vA2 + 1568);
            short8 nA2 = *(const short8*)(vA2 + 3136);

            f32x4 acc = {0.f, 0.f, 0.f, 0.f};
            acc = __builtin_amdgcn_mfma_f32_16x16x32_bf16(bfr[0],  *(const short8*)(vA0),        acc, 0, 0, 0);
            acc = __builtin_amdgcn_mfma_f32_16x16x32_bf16(bfr[1],  *(const short8*)(vA0 + 1568), acc, 0, 0, 0);
            acc = __builtin_amdgcn_mfma_f32_16x16x32_bf16(bfr[2],  *(const short8*)(vA0 + 3136), acc, 0, 0, 0);
            acc = __builtin_amdgcn_mfma_f32_16x16x32_bf16(bfr[3],  hA[jj][0],                    acc, 0, 0, 0);
            acc = __builtin_amdgcn_mfma_f32_16x16x32_bf16(bfr[4],  hA[jj][1],                    acc, 0, 0, 0);
            acc = __builtin_amdgcn_mfma_f32_16x16x32_bf16(bfr[5],  hA[jj][2],                    acc, 0, 0, 0);
            acc = __builtin_amdgcn_mfma_f32_16x16x32_bf16(bfr[6],  nA0,                          acc, 0, 0, 0);
            acc = __builtin_amdgcn_mfma_f32_16x16x32_bf16(bfr[7],  nA1,                          acc, 0, 0, 0);
            acc = __builtin_amdgcn_mfma_f32_16x16x32_bf16(bfr[8],  nA2,                          acc, 0, 0, 0);
            acc = __builtin_amdgcn_mfma_f32_16x16x32_bf16(bfr[9],  *(const short8*)(vB0),        acc, 0, 0, 0);
            acc = __builtin_amdgcn_mfma_f32_16x16x32_bf16(bfr[10], *(const short8*)(vB1),        acc, 0, 0, 0);
            acc = __builtin_amdgcn_mfma_f32_16x16x32_bf16(bfr[11], *(const short8*)(vB2),        acc, 0, 0, 0);
            acc = __builtin_amdgcn_mfma_f32_16x16x32_bf16(bfr[12], *(const short8*)(vC),         acc, 0, 0, 0);
            acc = __builtin_amdgcn_mfma_f32_16x16x32_bf16(bfr[13], *(const short8*)(vD),         acc, 0, 0, 0);

            // logM via MFMA: mean_ci of center tap (held center fragment)
            f32x4 am = __builtin_amdgcn_mfma_f32_16x16x32_bf16(
                aones, hA[jj][1], (f32x4){0.f, 0.f, 0.f, 0.f}, 0, 0, 0);
            const float lm = am[0];

            hA[jj][0] = nA0; hA[jj][1] = nA1; hA[jj][2] = nA2;

            // epilogue: D row m = 4q+t = cout, col n = mn = x -> 64 B-run stores
            float* op = ob + (size_t)(4 * q) * VOX
                      + (((size_t)z * 96 + (y0 + r)) * 96 + j * 16 + mn);
            #pragma unroll
            for (int t = 0; t < 4; ++t) {
                float e = fminf(fmaf(wa[t], lm, acc[t]), 126.0f);
                op[(size_t)t * VOX] = __builtin_amdgcn_exp2f(e);
            }
        }

        if (zi < ZC - 1) {
            // vmcnt(15) = this iter's 12 stores + 3 gll may remain in flight;
            // everything older (prev iter's gll + stores) has retired.  The plane
            // staged this iter is only read at iter+2, i.e. after the NEXT
            // barrier's vmcnt(15), which forces it to have landed.
            asm volatile("s_waitcnt vmcnt(15) lgkmcnt(0)" ::: "memory");
            __builtin_amdgcn_s_barrier();
            __builtin_amdgcn_sched_barrier(0);
        }
    }
}

// ---------------------------------------------------------------------------
// Fallback: previous harness-verified fused kernel (289.8 us), 16 KB workspace.
// (Stays in natural-log domain; self-consistent.)
// ---------------------------------------------------------------------------
#define FSLY  6
#define FROWS (SLX * 16)
#define FSS   (FSLY * FROWS)
#define FTY   4
#define FZC   6

__global__ void __launch_bounds__(256, 2)
mvc_main(const float* __restrict__ x,
         const short* __restrict__ w3,
         const float* __restrict__ wadj,
         float* __restrict__ out) {
    __shared__ __align__(16) short tile[3 * FSS];
    __shared__ float logMt[FTY * 96];

    const int tid  = threadIdx.x;
    const int lane = tid & 63;
    const int wv   = tid >> 6;
    const int mn   = lane & 15;
    const int q    = lane >> 4;
    const int qlo  = q & 1;
    const int qhi  = q >> 1;

    int id  = blockIdx.x;
    int xcd = id & 7, g = id >> 3;
    int yt  = xcd * 3 + g % 3;
    int rr  = g / 3;
    int zch = rr & 15, b = rr >> 4;
    const int y0 = yt * FTY;
    const int z0 = zch * FZC;

    const float* xb = x + (size_t)b * 16 * VOX;
    float* ob = out + (size_t)b * 16 * VOX;

    short8 bfr[14];
    #pragma unroll
    for (int p = 0; p < 14; ++p)
        bfr[p] = *(const short8*)(w3 + mn * 448 + p * 32 + q * 8);
    const float4 wv4 = *(const float4*)(wadj + 4 * q);
    const float wa[4] = {wv4.x, wv4.y, wv4.z, wv4.w};

    if (tid < 288) {
        int d = tid & 7, vv = tid >> 3;
        int bu = vv / 12, rv = vv % 12;
        int row = rv >> 1, side = rv & 1;
        ((unsigned*)tile)[bu * (FSS / 2) + (row * SLX + side * 97) * 8 + d] = 0u;
    }

    float2 h[5][4];

    auto load_plane = [&](int zp) {
        bool zin = (unsigned)zp < 96u;
        #pragma unroll
        for (int it = 0; it < 5; ++it) {
            if (it == 4 && tid >= 128) break;
            int slot = tid + it * 256;
            int cq = slot & 3;
            int t  = slot >> 2;
            int xp = t % 48;
            int y  = t / 48;
            int gy = y0 + y - 1;
            bool inb = zin && ((unsigned)gy < 96u);
            const float* p0 = xb + (size_t)(4 * cq) * VOX
                            + ((zp * 96 + gy) * 96 + 2 * xp);
            h[it][0] = inb ? *(const float2*)(p0)            : make_float2(1.f, 1.f);
            h[it][1] = inb ? *(const float2*)(p0 + VOX)      : make_float2(1.f, 1.f);
            h[it][2] = inb ? *(const float2*)(p0 + 2 * VOX)  : make_float2(1.f, 1.f);
            h[it][3] = inb ? *(const float2*)(p0 + 3 * VOX)  : make_float2(1.f, 1.f);
        }
    };
    auto write_plane = [&](int zp) {
        short* sb = tile + ((zp + 3) % 3) * FSS;
        #pragma unroll
        for (int it = 0; it < 5; ++it) {
            if (it == 4 && tid >= 128) break;
            int slot = tid + it * 256;
            int cq = slot & 3;
            int t  = slot >> 2;
            int xp = t % 48;
            int y  = t / 48;
            unsigned a0 = f2bf_rne(__logf(h[it][0].x)), a1 = f2bf_rne(__logf(h[it][1].x));
            unsigned a2 = f2bf_rne(__logf(h[it][2].x)), a3 = f2bf_rne(__logf(h[it][3].x));
            unsigned c0 = f2bf_rne(__logf(h[it][0].y)), c1 = f2bf_rne(__logf(h[it][1].y));
            unsigned c2 = f2bf_rne(__logf(h[it][2].y)), c3 = f2bf_rne(__logf(h[it][3].y));
            unsigned* dst = (unsigned*)(sb + (y * SLX + 1 + 2 * xp) * 16 + 4 * cq);
            *(uint2*)(dst)     = make_uint2(a0 | (a1 << 16), a2 | (a3 << 16));
            *(uint2*)(dst + 8) = make_uint2(c0 | (c1 << 16), c2 | (c3 << 16));
        }
    };
    auto do_logM = [&](int z) {
        const short* cb = tile + (z % 3) * FSS;
        #pragma unroll
        for (int it = 0; it < 2; ++it) {
            if (it == 1 && tid >= 128) break;
            int v = tid + it * 256;
            int xx = v % 96, yy = v / 96;
            const short* p = cb + ((yy + 1) * SLX + (xx + 1)) * 16;
            short8 h0 = *(const short8*)p;
            short8 h1 = *(const short8*)(p + 8);
            float s = 0.f;
            #pragma unroll
            for (int c = 0; c < 8; ++c) s += bf2f(h0[c]) + bf2f(h1[c]);
            logMt[v] = s * 0.0625f;
        }
    };

    load_plane(z0 - 1); write_plane(z0 - 1);
    load_plane(z0);     write_plane(z0);
    load_plane(z0 + 1); write_plane(z0 + 1);
    __syncthreads();

    for (int zi = 0; zi < FZC; ++zi) {
        const int z = z0 + zi;
        const bool st = (zi < FZC - 1);
        if (st) load_plane(z + 2);
        do_logM(z);
        __syncthreads();

        const int B0 = ((z + 2) % 3) * FSS;
        const int B1 = (z % 3) * FSS;
        const int B2 = ((z + 1) % 3) * FSS;
        const int Lb = mn * 16 + qlo * 8 + wv * FROWS + qhi * 16;

        #pragma unroll
        for (int j = 0; j < 6; ++j) {
            const short* vA0 = tile + (Lb + j * 256 + B0);
            const short* vA1 = tile + (Lb + j * 256 + B1);
            const short* vA2 = tile + (Lb + j * 256 + B2);
            const short* vB0 = vA0 + 32 + qhi * 1552;
            const short* vB1 = vA1 + 32 + qhi * 1552;
            const short* vB2 = vA2 + 32 + qhi * 1552;
            const short* vD  = vB2 + (3136 - qhi * 1584);
            const short* vC  = vD - B2 + (qhi ? B1 : B0);

            f32x4 acc = {0.f, 0.f, 0.f, 0.f};
            acc = __builtin_amdgcn_mfma_f32_16x16x32_bf16(bfr[0],  *(const short8*)(vA0),        acc, 0, 0, 0);
            acc = __builtin_amdgcn_mfma_f32_16x16x32_bf16(bfr[1],  *(const short8*)(vA0 + 1568), acc, 0, 0, 0);
            acc = __builtin_amdgcn_mfma_f32_16x16x32_bf16(bfr[2],  *(const short8*)(vA0 + 3136), acc, 0, 0, 0);
            acc = __builtin_amdgcn_mfma_f32_16x16x32_bf16(bfr[3],  *(const short8*)(vA1),        acc, 0, 0, 0);
            acc = __builtin_amdgcn_mfma_f32_16x16x32_bf16(bfr[4],  *(const short8*)(vA1 + 1568), acc, 0, 0, 0);
            acc = __builtin_amdgcn_mfma_f32_16x16x32_bf16(bfr[5],  *(const short8*)(vA1 + 3136), acc, 0, 0, 0);
            acc = __builtin_amdgcn_mfma_f32_16x16x32_bf16(bfr[6],  *(const short8*)(vA2),        acc, 0, 0, 0);
            acc = __builtin_amdgcn_mfma_f32_16x16x32_bf16(bfr[7],  *(const short8*)(vA2 + 1568), acc, 0, 0, 0);
            acc = __builtin_amdgcn_mfma_f32_16x16x32_bf16(bfr[8],  *(const short8*)(vA2 + 3136), acc, 0, 0, 0);
            acc = __builtin_amdgcn_mfma_f32_16x16x32_bf16(bfr[9],  *(const short8*)(vB0),        acc, 0, 0, 0);
            acc = __builtin_amdgcn_mfma_f32_16x16x32_bf16(bfr[10], *(const short8*)(vB1),        acc, 0, 0, 0);
            acc = __builtin_amdgcn_mfma_f32_16x16x32_bf16(bfr[11], *(const short8*)(vB2),        acc, 0, 0, 0);
            acc = __builtin_amdgcn_mfma_f32_16x16x32_bf16(bfr[12], *(const short8*)(vC),         acc, 0, 0, 0);
            acc = __builtin_amdgcn_mfma_f32_16x16x32_bf16(bfr[13], *(const short8*)(vD),         acc, 0, 0, 0);

            float lm = logMt[wv * 96 + j * 16 + mn];
            float* op = ob + (size_t)(4 * q) * VOX
                      + (((size_t)z * 96 + (y0 + wv)) * 96 + j * 16 + mn);
            #pragma unroll
            for (int t = 0; t < 4; ++t) {
                float e = fminf(fmaf(wa[t], lm, acc[t]), 88.0f);
                op[(size_t)t * VOX] = __expf(e);
            }
        }
        __syncthreads();
        if (st) write_plane(z + 2);
    }
}

extern "C" void kernel_launch(void* const* d_in, const int* in_sizes, int n_in,
                              void* d_out, int out_size, void* d_ws, size_t ws_size,
                              hipStream_t stream) {
    const float* x = (const float*)d_in[0];
    const float* w = (const float*)d_in[1];
    float* out  = (float*)d_out;
    short* w3   = (short*)d_ws;                          // 16*448 bf16 = 14336 B
    float* wadj = (float*)((char*)d_ws + 14336);         // 16 floats
    short* lgx  = (short*)((char*)d_ws + 16384);         // logx scratch

    const size_t lx_full = (size_t)2 * VOX * 16 * 2;     // 56.6 MB (both batches)
    const size_t lx_half = (size_t)VOX * 16 * 2;         // 28.3 MB (one batch)

    if (ws_size >= 16384 + lx_full) {
        // Full path: merged log+reorg pass, then one conv pass.
        hipLaunchKernelGGL(mvc_logr, dim3(6940), dim3(256), 0, stream,
                           x, lgx, w, w3, wadj);
        hipLaunchKernelGGL(mvc_conv, dim3(768),  dim3(256), 0, stream,
                           lgx, w3, wadj, out);
    } else if (ws_size >= 16384 + lx_half) {
        // Per-batch path: half-size scratch, serialized batches.
        hipLaunchKernelGGL(mvc_reorg, dim3(28), dim3(256), 0, stream, w, w3, wadj);
        for (int b = 0; b < 2; ++b) {
            hipLaunchKernelGGL(mvc_log,  dim3(3456), dim3(256), 0, stream,
                               x + (size_t)b * 16 * VOX, lgx);
            hipLaunchKernelGGL(mvc_conv, dim3(384),  dim3(256), 0, stream,
                               lgx, w3, wadj, out + (size_t)b * 16 * VOX);
        }
    } else {
        // Fallback: harness-verified fused kernel (16 KB workspace only).
        hipLaunchKernelGGL(mvc_reorg, dim3(28), dim3(256), 0, stream, w, w3, wadj);
        hipLaunchKernelGGL(mvc_main, dim3(768), dim3(256), 0, stream, x, w3, wadj, out);
    }
}